// Round 1
// baseline (167.016 us; speedup 1.0000x reference)
//
#include <hip/hip_runtime.h>

// HBilinearUpsample: Poincare-ball geodesic-midpoint 2x upsample.
// Key identity: midpoint(x,y) = A*x + B*y with scalars A,B computed from
// (|x|^2, |y|^2, x.y) only:
//   w = mobius(-x,y) = (-alpha*x + beta*y)/den_w,
//     alpha = 1-2xy+y2, beta = 1-x2, den_w = 1-2xy+x2*y2
//   tanh(0.5*atanh(r)) = r/(1+sqrt(1-r^2))    (lam cancels exactly)
//   second = t*w, t = s/wn, s = a/(1+sqrt(1-a^2)), a = min(wn, 1-1e-5)
//   mid = [(1+2xs+s2)*x + beta*second]/den
// Center of a 2x2 cell = midpoint(midpoint(x00,x10), midpoint(x01,x11)),
// which stays a linear combo of the 4 corners with coefficients from the
// 4x4 Gram matrix. Edge replication == clamped neighbor index (mid(x,x)=x).

#define EPSF   1e-15f
#define MAXAT  0.99999f

__device__ __forceinline__ void midcoef(float x2, float y2, float xy,
                                        float& A, float& B) {
    float alpha  = 1.0f - 2.0f * xy + y2;
    float beta   = 1.0f - x2;
    float den_w  = fmaxf(1.0f - 2.0f * xy + x2 * y2, EPSF);
    float inv_dw = 1.0f / den_w;
    // dot(x, w)
    float dxw = (beta * xy - alpha * x2) * inv_dw;
    // |w|^2
    float wn2 = (alpha * alpha * x2 - 2.0f * alpha * beta * xy + beta * beta * y2)
                * inv_dw * inv_dw;
    wn2 = fmaxf(wn2, EPSF);
    float wn = sqrtf(wn2);
    float a  = fminf(wn, MAXAT);
    float s  = a / (1.0f + sqrtf(fmaxf(1.0f - a * a, 0.0f)));
    float t  = s / wn;                 // second = t * w
    float xs = t * dxw;                // dot(x, second)
    float s2 = t * t * wn2;            // |second|^2
    float den     = fmaxf(1.0f + 2.0f * xs + x2 * s2, EPSF);
    float inv_den = 1.0f / den;
    float k = beta * t * inv_dw;
    A = (1.0f + 2.0f * xs + s2 - k * alpha * 0.0f) * inv_den - k * alpha * inv_den;
    // (written as two terms to keep fp order simple)
    A = ((1.0f + 2.0f * xs + s2) - k * alpha) * inv_den;
    B = (k * beta) * inv_den;
}

__global__ __launch_bounds__(128)
void hupsample_kernel(const float* __restrict__ x, float* __restrict__ out) {
    constexpr int B = 8, C = 64, H = 128, W = 128;
    constexpr int CS = H * W;            // channel stride (elems)
    const int w  = threadIdx.x;          // 0..127
    const int h  = blockIdx.x;           // 0..127
    const int b  = blockIdx.y;           // 0..7
    const int wp = (w + 1 < W) ? (w + 1) : (W - 1);
    const int hp = (h + 1 < H) ? (h + 1) : (H - 1);

    const float* xb  = x + (size_t)b * C * CS;
    const float* p00 = xb + h  * W + w;
    const float* p10 = xb + h  * W + wp;
    const float* p01 = xb + hp * W + w;
    const float* p11 = xb + hp * W + wp;

    // ---- pass 1: Gram matrix of the 4 corners (reduce over channels) ----
    float g00 = 0.f, g10 = 0.f, g01 = 0.f, g11 = 0.f;
    float d0010 = 0.f, d0111 = 0.f, d0001 = 0.f;
    float d0011 = 0.f, d1001 = 0.f, d1011 = 0.f;
#pragma unroll 4
    for (int c = 0; c < C; ++c) {
        float v00 = p00[c * CS];
        float v10 = p10[c * CS];
        float v01 = p01[c * CS];
        float v11 = p11[c * CS];
        g00   += v00 * v00;  g10   += v10 * v10;
        g01   += v01 * v01;  g11   += v11 * v11;
        d0010 += v00 * v10;  d0111 += v01 * v11;
        d0001 += v00 * v01;  d0011 += v00 * v11;
        d1001 += v10 * v01;  d1011 += v10 * v11;
    }

    // ---- scalar coefficients ----
    float Ah, Bh;  midcoef(g00, g10, d0010, Ah, Bh);   // horizontal mid, row h
    float A2, B2;  midcoef(g01, g11, d0111, A2, B2);   // horizontal mid, row h+1
    float Av, Bv;  midcoef(g00, g01, d0001, Av, Bv);   // vertical mid

    // center = midpoint(a_vec, b_vec); Gram entries of a_vec = Ah*x00+Bh*x10,
    // b_vec = A2*x01+B2*x11:
    float a2 = Ah * Ah * g00 + 2.0f * Ah * Bh * d0010 + Bh * Bh * g10;
    float b2 = A2 * A2 * g01 + 2.0f * A2 * B2 * d0111 + B2 * B2 * g11;
    float ab = Ah * A2 * d0001 + Ah * B2 * d0011 + Bh * A2 * d1001 + Bh * B2 * d1011;
    float A3, B3;  midcoef(a2, b2, ab, A3, B3);
    float CA = A3 * Ah, CB = A3 * Bh, CC = B3 * A2, CD = B3 * B2;

    // ---- pass 2: emit 2x2 output cell per channel ----
    float* ob = out + (size_t)b * C * (2 * H) * (2 * W);
    const size_t rbase = (size_t)(2 * h) * (2 * W) + (size_t)(2 * w);
#pragma unroll 4
    for (int c = 0; c < C; ++c) {
        float v00 = p00[c * CS];
        float v10 = p10[c * CS];
        float v01 = p01[c * CS];
        float v11 = p11[c * CS];
        float oh = Ah * v00 + Bh * v10;
        float ov = Av * v00 + Bv * v01;
        float oc = CA * v00 + CB * v10 + CC * v01 + CD * v11;
        size_t base = (size_t)c * (4 * CS) + rbase;
        *(float2*)(ob + base)             = make_float2(v00, oh);
        *(float2*)(ob + base + 2 * W)     = make_float2(ov, oc);
    }
}

extern "C" void kernel_launch(void* const* d_in, const int* in_sizes, int n_in,
                              void* d_out, int out_size, void* d_ws, size_t ws_size,
                              hipStream_t stream) {
    const float* x = (const float*)d_in[0];
    float* out = (float*)d_out;
    dim3 grid(128, 8);   // (h, b)
    dim3 block(128);     // w
    hipLaunchKernelGGL(hupsample_kernel, grid, block, 0, stream, x, out);
}